// Round 1
// baseline (3423.697 us; speedup 1.0000x reference)
//
#include <hip/hip_runtime.h>

#define NB 32
#define N 512
#define MAT (N*N)   // 262144

// ---------------- luma: y = .299 x0 + .587 x1 + .114 x2 ----------------
__global__ __launch_bounds__(256) void k_luma(const float* __restrict__ x, float* __restrict__ y) {
    int tid = blockIdx.x * 256 + threadIdx.x;      // over float4s: 32 * 65536
    int b = tid >> 16;                             // 65536 float4 per image plane
    int p = tid & 65535;
    const float4* xb = (const float4*)(x + (size_t)b * 3 * MAT);
    float4 r = xb[p];
    float4 g = xb[p + MAT/4];
    float4 bl = xb[p + MAT/2];
    float4 o;
    o.x = 0.299f*r.x + 0.587f*g.x + 0.114f*bl.x;
    o.y = 0.299f*r.y + 0.587f*g.y + 0.114f*bl.y;
    o.z = 0.299f*r.z + 0.587f*g.z + 0.114f*bl.z;
    o.w = 0.299f*r.w + 0.587f*g.w + 0.114f*bl.w;
    ((float4*)(y + (size_t)b * MAT))[p] = o;
}

// ---------------- per-batch Frobenius norm -> rscale = 1/||B||_F ----------------
__global__ __launch_bounds__(256) void k_frob(const float* __restrict__ B, float* __restrict__ rs) {
    int b = blockIdx.x;
    const float4* Bb = (const float4*)(B + (size_t)b * MAT);
    float s = 0.f;
    for (int i = threadIdx.x; i < MAT/4; i += 256) {
        float4 v = Bb[i];
        s += v.x*v.x + v.y*v.y + v.z*v.z + v.w*v.w;
    }
    for (int o = 32; o; o >>= 1) s += __shfl_down(s, o, 64);
    __shared__ float red[4];
    int lane = threadIdx.x & 63, wv = threadIdx.x >> 6;
    if (lane == 0) red[wv] = s;
    __syncthreads();
    if (threadIdx.x == 0) {
        float t = red[0] + red[1] + red[2] + red[3];
        rs[b] = rsqrtf(t);
    }
}

// ---------------- C = alpha^2 * A^T A  (A: 512x512 row-major, per batch) ----------------
// 64x64 tile per block, BK=16, 256 threads, 4x4 per thread.
#define BM 64
#define BN 64
#define BK 16
__global__ __launch_bounds__(256) void k_gemm_ata(const float* __restrict__ A, float* __restrict__ C,
                                                  const float* __restrict__ rs) {
    int b = blockIdx.z;
    const float* Ab = A + (size_t)b * MAT;
    float* Cb = C + (size_t)b * MAT;
    float alpha = 1.0f;
    if (rs) { float r = rs[b]; alpha = r * r; }

    __shared__ float As[BK][BM];   // A[k][i-block]
    __shared__ float Bs[BK][BN];   // A[k][j-block]

    int t = threadIdx.x;
    int tx = t & 15, ty = t >> 4;
    int iBase = blockIdx.y * BM, jBase = blockIdx.x * BN;
    int lc = t & 63, lr = t >> 6;   // load: col 0..63, row-group 0..3

    float acc[4][4];
    #pragma unroll
    for (int i = 0; i < 4; ++i)
        #pragma unroll
        for (int j = 0; j < 4; ++j) acc[i][j] = 0.f;

    for (int k0 = 0; k0 < N; k0 += BK) {
        #pragma unroll
        for (int r = 0; r < 4; ++r) {
            int k = lr * 4 + r;
            As[k][lc] = Ab[(size_t)(k0 + k) * N + iBase + lc];
            Bs[k][lc] = Ab[(size_t)(k0 + k) * N + jBase + lc];
        }
        __syncthreads();
        #pragma unroll
        for (int k = 0; k < BK; ++k) {
            float4 a = *(const float4*)&As[k][ty * 4];
            float4 bb = *(const float4*)&Bs[k][tx * 4];
            float av[4] = {a.x, a.y, a.z, a.w};
            float bv[4] = {bb.x, bb.y, bb.z, bb.w};
            #pragma unroll
            for (int i = 0; i < 4; ++i)
                #pragma unroll
                for (int j = 0; j < 4; ++j) acc[i][j] += av[i] * bv[j];
        }
        __syncthreads();
    }
    #pragma unroll
    for (int i = 0; i < 4; ++i) {
        float4 o;
        o.x = acc[i][0] * alpha; o.y = acc[i][1] * alpha;
        o.z = acc[i][2] * alpha; o.w = acc[i][3] * alpha;
        *(float4*)&Cb[(size_t)(iBase + ty * 4 + i) * N + jBase + tx * 4] = o;
    }
}

// ---------------- power iteration on Cm (=B^32), then w = Y v ----------------
__global__ __launch_bounds__(512) void k_power(const float* __restrict__ Cm, const float* __restrict__ Y,
                                               float* __restrict__ vout, float* __restrict__ wout, int iters) {
    int b = blockIdx.x;
    const float* C = Cm + (size_t)b * MAT;
    const float* Yb = Y + (size_t)b * MAT;
    __shared__ float vs[N];
    __shared__ float wn[N];
    __shared__ float red[8];
    __shared__ float snorm;
    int t = threadIdx.x, lane = t & 63, wv = t >> 6;   // 8 waves, 64 rows each
    {
        unsigned h = (unsigned)t * 1103515245u + 12345u;
        vs[t] = (float)((h >> 16) & 0x7fff) / 16384.f - 1.f;
    }
    __syncthreads();

    int rbase = wv * 64;
    for (int it = 0; it < iters; ++it) {
        // wn = C * vs   (each wave: 64 rows, coalesced 64-lane column chunks)
        for (int g = 0; g < 8; ++g) {
            float acc[8] = {0,0,0,0,0,0,0,0};
            #pragma unroll
            for (int c = 0; c < 8; ++c) {
                float vvl = vs[c * 64 + lane];
                #pragma unroll
                for (int q = 0; q < 8; ++q)
                    acc[q] += C[(size_t)(rbase + g * 8 + q) * N + c * 64 + lane] * vvl;
            }
            #pragma unroll
            for (int q = 0; q < 8; ++q) {
                float s = acc[q];
                for (int o = 32; o; o >>= 1) s += __shfl_xor(s, o, 64);
                if (lane == 0) wn[rbase + g * 8 + q] = s;
            }
        }
        __syncthreads();
        // normalize
        float val = wn[t];
        float ss = val * val;
        for (int o = 32; o; o >>= 1) ss += __shfl_xor(ss, o, 64);
        if (lane == 0) red[wv] = ss;
        __syncthreads();
        if (t == 0) {
            float tt = 0.f;
            for (int i = 0; i < 8; ++i) tt += red[i];
            snorm = rsqrtf(tt);
        }
        __syncthreads();
        vs[t] = val * snorm;
        __syncthreads();
    }

    // w = Y * v  (= sigma * u, unnormalized)
    for (int g = 0; g < 8; ++g) {
        float acc[8] = {0,0,0,0,0,0,0,0};
        #pragma unroll
        for (int c = 0; c < 8; ++c) {
            float vvl = vs[c * 64 + lane];
            #pragma unroll
            for (int q = 0; q < 8; ++q)
                acc[q] += Yb[(size_t)(rbase + g * 8 + q) * N + c * 64 + lane] * vvl;
        }
        #pragma unroll
        for (int q = 0; q < 8; ++q) {
            float s = acc[q];
            for (int o = 32; o; o >>= 1) s += __shfl_xor(s, o, 64);
            if (lane == 0) wn[rbase + g * 8 + q] = s;
        }
    }
    __syncthreads();
    vout[(size_t)b * N + t] = vs[t];
    wout[(size_t)b * N + t] = wn[t];
}

// ---------------- out[b,i,j] = w[b,i] * v[b,j] ----------------
__global__ __launch_bounds__(256) void k_outer(const float* __restrict__ v, const float* __restrict__ w,
                                               float* __restrict__ out) {
    int tid = blockIdx.x * 256 + threadIdx.x;   // 2,097,152 float4
    int b = tid >> 16;
    int rem = tid & 65535;
    int i = rem >> 7;
    int j4 = rem & 127;
    float wi = w[(size_t)b * N + i];
    float4 vv = ((const float4*)(v + (size_t)b * N))[j4];
    float4 o = {wi * vv.x, wi * vv.y, wi * vv.z, wi * vv.w};
    ((float4*)out)[tid] = o;
}

extern "C" void kernel_launch(void* const* d_in, const int* in_sizes, int n_in,
                              void* d_out, int out_size, void* d_ws, size_t ws_size,
                              hipStream_t stream) {
    const float* x = (const float*)d_in[0];
    float* out = (float*)d_out;
    float* f = (float*)d_ws;

    float* Ba = f;                                // 32 * 262144 floats
    float* Bb = f + (size_t)NB * MAT;             // 32 * 262144 floats
    float* rs = f + (size_t)2 * NB * MAT;         // 32 floats (pad to 64)
    float* vv = rs + 64;                          // 32 * 512
    float* ww = vv + (size_t)NB * N;              // 32 * 512
    float* y = out;                               // stage luma in d_out (overwritten at the end)

    k_luma<<<8192, 256, 0, stream>>>(x, y);

    dim3 gg(N / BN, N / BM, NB);
    // B0 = y^T y
    k_gemm_ata<<<gg, 256, 0, stream>>>(y, Ba, nullptr);
    // 5 squarings with Frobenius renormalization: B32 ends in Bb
    for (int s = 0; s < 5; ++s) {
        float* src = (s & 1) ? Bb : Ba;
        float* dst = (s & 1) ? Ba : Bb;
        k_frob<<<NB, 256, 0, stream>>>(src, rs);
        k_gemm_ata<<<gg, 256, 0, stream>>>(src, dst, rs);
    }
    k_power<<<NB, 512, 0, stream>>>(Bb, y, vv, ww, 96);
    k_outer<<<8192, 256, 0, stream>>>(vv, ww, out);
}

// Round 2
// 1218.723 us; speedup vs baseline: 2.8092x; 2.8092x over previous
//
#include <hip/hip_runtime.h>

#define NB 32
#define N 512
#define MAT (N*N)   // 262144

// ---------------- luma: y = .299 x0 + .587 x1 + .114 x2 ----------------
__global__ __launch_bounds__(256) void k_luma(const float* __restrict__ x, float* __restrict__ y) {
    int tid = blockIdx.x * 256 + threadIdx.x;      // over float4s: 32 * 65536
    int b = tid >> 16;
    int p = tid & 65535;
    const float4* xb = (const float4*)(x + (size_t)b * 3 * MAT);
    float4 r = xb[p];
    float4 g = xb[p + MAT/4];
    float4 bl = xb[p + MAT/2];
    float4 o;
    o.x = 0.299f*r.x + 0.587f*g.x + 0.114f*bl.x;
    o.y = 0.299f*r.y + 0.587f*g.y + 0.114f*bl.y;
    o.z = 0.299f*r.z + 0.587f*g.z + 0.114f*bl.z;
    o.w = 0.299f*r.w + 0.587f*g.w + 0.114f*bl.w;
    ((float4*)(y + (size_t)b * MAT))[p] = o;
}

// ---------------- C = alpha * A^T A, alpha = 1/frob2_src; frob2 of C -> fdst ----------------
// 128x128 tile, 256 threads, 8x8 microtile (2x2 quadrants of 4x4), BK=16.
#define TM 128
#define TK 16
__global__ __launch_bounds__(256) void k_gemm(const float* __restrict__ A, float* __restrict__ C,
                                              const float* __restrict__ fsrc, float* __restrict__ fdst) {
    int b = blockIdx.z;
    const float* Ab = A + (size_t)b * MAT;
    float* Cb = C + (size_t)b * MAT;

    __shared__ __align__(16) float As[TK][TM];
    __shared__ __align__(16) float Bs[TK][TM];

    int t = threadIdx.x;
    int iBase = blockIdx.y * TM, jBase = blockIdx.x * TM;
    int lr = t >> 5;            // 0..7
    int lc = (t & 31) << 2;     // 0,4,...,124
    int tx = t & 15, ty = t >> 4;

    float alpha = fsrc ? (1.0f / fsrc[b]) : 1.0f;

    float acc[2][2][4][4] = {};

    for (int k0 = 0; k0 < N; k0 += TK) {
        *(float4*)&As[lr][lc]   = *(const float4*)&Ab[(size_t)(k0 + lr) * N + iBase + lc];
        *(float4*)&As[lr+8][lc] = *(const float4*)&Ab[(size_t)(k0 + lr + 8) * N + iBase + lc];
        *(float4*)&Bs[lr][lc]   = *(const float4*)&Ab[(size_t)(k0 + lr) * N + jBase + lc];
        *(float4*)&Bs[lr+8][lc] = *(const float4*)&Ab[(size_t)(k0 + lr + 8) * N + jBase + lc];
        __syncthreads();
        #pragma unroll
        for (int k = 0; k < TK; ++k) {
            float4 a0 = *(float4*)&As[k][ty * 4];
            float4 a1 = *(float4*)&As[k][ty * 4 + 64];
            float4 b0 = *(float4*)&Bs[k][tx * 4];
            float4 b1 = *(float4*)&Bs[k][tx * 4 + 64];
            float av[2][4] = {{a0.x,a0.y,a0.z,a0.w},{a1.x,a1.y,a1.z,a1.w}};
            float bv[2][4] = {{b0.x,b0.y,b0.z,b0.w},{b1.x,b1.y,b1.z,b1.w}};
            #pragma unroll
            for (int iq = 0; iq < 2; ++iq)
                #pragma unroll
                for (int i = 0; i < 4; ++i)
                    #pragma unroll
                    for (int jq = 0; jq < 2; ++jq)
                        #pragma unroll
                        for (int j = 0; j < 4; ++j)
                            acc[iq][jq][i][j] += av[iq][i] * bv[jq][j];
        }
        __syncthreads();
    }

    float ss = 0.f;
    #pragma unroll
    for (int iq = 0; iq < 2; ++iq)
        #pragma unroll
        for (int i = 0; i < 4; ++i) {
            int row = iBase + iq * 64 + ty * 4 + i;
            #pragma unroll
            for (int jq = 0; jq < 2; ++jq) {
                float4 o;
                o.x = acc[iq][jq][i][0] * alpha;
                o.y = acc[iq][jq][i][1] * alpha;
                o.z = acc[iq][jq][i][2] * alpha;
                o.w = acc[iq][jq][i][3] * alpha;
                ss += o.x*o.x + o.y*o.y + o.z*o.z + o.w*o.w;
                *(float4*)&Cb[(size_t)row * N + jBase + jq * 64 + tx * 4] = o;
            }
        }

    if (fdst) {
        for (int o = 32; o; o >>= 1) ss += __shfl_down(ss, o, 64);
        __shared__ float red[4];
        int lane = t & 63, wv = t >> 6;
        if (lane == 0) red[wv] = ss;
        __syncthreads();
        if (t == 0) atomicAdd(&fdst[b], red[0] + red[1] + red[2] + red[3]);
    }
}

// ---------------- power iteration on symmetric Cm (=B^128), then w = Y v ----------------
// Thread t owns row t. Symmetry: w[t] = sum_c C[t][c] v[c] = sum_c C[c][t] v[c]
// -> column access = coalesced. No per-iteration normalization (frob-normalized
// B^128 has lambda1 ~ 0.8-1; norm drift over 24 iters is benign in fp32).
__global__ __launch_bounds__(512) void k_power(const float* __restrict__ Cm, const float* __restrict__ Y,
                                               float* __restrict__ vout, float* __restrict__ wout, int iters) {
    int b = blockIdx.x;
    const float* C = Cm + (size_t)b * MAT;
    const float* Yb = Y + (size_t)b * MAT;
    __shared__ __align__(16) float va[N];
    __shared__ __align__(16) float vb[N];
    __shared__ float red[8];
    __shared__ float snorm;
    int t = threadIdx.x, lane = t & 63, wv = t >> 6;

    unsigned h = (unsigned)t * 1103515245u + 12345u;
    va[t] = (float)((h >> 16) & 0x7fff) / 16384.f - 1.f;
    __syncthreads();

    const float* Ct = C + t;
    for (int it = 0; it < iters; ++it) {
        float* src = (it & 1) ? vb : va;
        float* dst = (it & 1) ? va : vb;
        float acc = 0.f;
        #pragma unroll 4
        for (int c = 0; c < N; c += 8) {
            float4 s0 = *(const float4*)&src[c];
            float4 s1 = *(const float4*)&src[c + 4];
            const float* p = Ct + (size_t)c * N;
            acc += p[0 * N] * s0.x;
            acc += p[1 * N] * s0.y;
            acc += p[2 * N] * s0.z;
            acc += p[3 * N] * s0.w;
            acc += p[4 * N] * s1.x;
            acc += p[5 * N] * s1.y;
            acc += p[6 * N] * s1.z;
            acc += p[7 * N] * s1.w;
        }
        dst[t] = acc;
        __syncthreads();
    }

    // normalize final vector
    float* fin = (iters & 1) ? vb : va;
    float* oth = (iters & 1) ? va : vb;
    float val = fin[t];
    float ss = val * val;
    for (int o = 32; o; o >>= 1) ss += __shfl_xor(ss, o, 64);
    if (lane == 0) red[wv] = ss;
    __syncthreads();
    if (t == 0) {
        float tt = 0.f;
        #pragma unroll
        for (int i = 0; i < 8; ++i) tt += red[i];
        snorm = rsqrtf(tt);
    }
    __syncthreads();
    fin[t] = val * snorm;
    __syncthreads();

    // w = Y * v_hat  (Y not symmetric: wave-mapped rows + shuffle reduce, once)
    int rbase = wv * 64;
    for (int g = 0; g < 8; ++g) {
        float accw[8] = {0,0,0,0,0,0,0,0};
        #pragma unroll
        for (int c = 0; c < 8; ++c) {
            float vvl = fin[c * 64 + lane];
            #pragma unroll
            for (int q = 0; q < 8; ++q)
                accw[q] += Yb[(size_t)(rbase + g * 8 + q) * N + c * 64 + lane] * vvl;
        }
        #pragma unroll
        for (int q = 0; q < 8; ++q) {
            float s = accw[q];
            for (int o = 32; o; o >>= 1) s += __shfl_xor(s, o, 64);
            if (lane == 0) oth[rbase + g * 8 + q] = s;
        }
    }
    __syncthreads();
    vout[(size_t)b * N + t] = fin[t];
    wout[(size_t)b * N + t] = oth[t];
}

// ---------------- out[b,i,j] = w[b,i] * v[b,j] ----------------
__global__ __launch_bounds__(256) void k_outer(const float* __restrict__ v, const float* __restrict__ w,
                                               float* __restrict__ out) {
    int tid = blockIdx.x * 256 + threadIdx.x;   // 2,097,152 float4
    int b = tid >> 16;
    int rem = tid & 65535;
    int i = rem >> 7;
    int j4 = rem & 127;
    float wi = w[(size_t)b * N + i];
    float4 vv = ((const float4*)(v + (size_t)b * N))[j4];
    float4 o = {wi * vv.x, wi * vv.y, wi * vv.z, wi * vv.w};
    ((float4*)out)[tid] = o;
}

extern "C" void kernel_launch(void* const* d_in, const int* in_sizes, int n_in,
                              void* d_out, int out_size, void* d_ws, size_t ws_size,
                              hipStream_t stream) {
    const float* x = (const float*)d_in[0];
    float* out = (float*)d_out;
    float* f = (float*)d_ws;

    float* Ba = f;                                // 32 MB
    float* Bb = f + (size_t)NB * MAT;             // 32 MB
    float* fs = f + (size_t)2 * NB * MAT;         // 7*32 floats frob2 accumulators
    float* vv = fs + 7 * 32;                      // 32*512
    float* ww = vv + (size_t)NB * N;              // 32*512
    float* y  = out;                              // stage luma in d_out

    hipMemsetAsync(fs, 0, 7 * 32 * sizeof(float), stream);
    k_luma<<<8192, 256, 0, stream>>>(x, y);

    dim3 gg(N / TM, N / TM, NB);   // 4 x 4 x 32
    k_gemm<<<gg, 256, 0, stream>>>(y,  Ba, nullptr,      fs + 0*32);  // B
    k_gemm<<<gg, 256, 0, stream>>>(Ba, Bb, fs + 0*32,    fs + 1*32);  // B^2
    k_gemm<<<gg, 256, 0, stream>>>(Bb, Ba, fs + 1*32,    fs + 2*32);  // B^4
    k_gemm<<<gg, 256, 0, stream>>>(Ba, Bb, fs + 2*32,    fs + 3*32);  // B^8
    k_gemm<<<gg, 256, 0, stream>>>(Bb, Ba, fs + 3*32,    fs + 4*32);  // B^16
    k_gemm<<<gg, 256, 0, stream>>>(Ba, Bb, fs + 4*32,    fs + 5*32);  // B^32
    k_gemm<<<gg, 256, 0, stream>>>(Bb, Ba, fs + 5*32,    fs + 6*32);  // B^64
    k_gemm<<<gg, 256, 0, stream>>>(Ba, Bb, fs + 6*32,    nullptr);    // B^128 -> Bb

    k_power<<<NB, 512, 0, stream>>>(Bb, y, vv, ww, 24);
    k_outer<<<8192, 256, 0, stream>>>(vv, ww, out);
}

// Round 3
// 934.366 us; speedup vs baseline: 3.6642x; 1.3043x over previous
//
#include <hip/hip_runtime.h>

#define NB 32
#define N 512
#define MAT (N*N)   // 262144

typedef short short8 __attribute__((ext_vector_type(8)));
typedef float f32x4 __attribute__((ext_vector_type(4)));

__device__ inline unsigned short f2bf(float x) {
    unsigned u = __float_as_uint(x);
    return (unsigned short)((u + 0x7FFFu + ((u >> 16) & 1u)) >> 16);
}
__device__ inline float bf2f(unsigned short h) {
    return __uint_as_float(((unsigned)h) << 16);
}

// ---------------- luma: y = .299 x0 + .587 x1 + .114 x2 ----------------
__global__ __launch_bounds__(256) void k_luma(const float* __restrict__ x, float* __restrict__ y) {
    int tid = blockIdx.x * 256 + threadIdx.x;
    int b = tid >> 16;
    int p = tid & 65535;
    const float4* xb = (const float4*)(x + (size_t)b * 3 * MAT);
    float4 r = xb[p];
    float4 g = xb[p + MAT/4];
    float4 bl = xb[p + MAT/2];
    float4 o;
    o.x = 0.299f*r.x + 0.587f*g.x + 0.114f*bl.x;
    o.y = 0.299f*r.y + 0.587f*g.y + 0.114f*bl.y;
    o.z = 0.299f*r.z + 0.587f*g.z + 0.114f*bl.z;
    o.w = 0.299f*r.w + 0.587f*g.w + 0.114f*bl.w;
    ((float4*)(y + (size_t)b * MAT))[p] = o;
}

// ---------------- fp32 VALU GEMM (used ONLY for P1 = y^T y; proven in R2) ----------------
#define TM 128
#define TK 16
__global__ __launch_bounds__(256) void k_gemm_f32(const float* __restrict__ A, float* __restrict__ C,
                                                  const float* __restrict__ fsrc, float* __restrict__ fdst) {
    int b = blockIdx.z;
    const float* Ab = A + (size_t)b * MAT;
    float* Cb = C + (size_t)b * MAT;

    __shared__ __align__(16) float As[TK][TM];
    __shared__ __align__(16) float Bs[TK][TM];

    int t = threadIdx.x;
    int iBase = blockIdx.y * TM, jBase = blockIdx.x * TM;
    int lr = t >> 5;
    int lc = (t & 31) << 2;
    int tx = t & 15, ty = t >> 4;

    float alpha = fsrc ? (1.0f / fsrc[b]) : 1.0f;

    float acc[2][2][4][4] = {};

    for (int k0 = 0; k0 < N; k0 += TK) {
        *(float4*)&As[lr][lc]   = *(const float4*)&Ab[(size_t)(k0 + lr) * N + iBase + lc];
        *(float4*)&As[lr+8][lc] = *(const float4*)&Ab[(size_t)(k0 + lr + 8) * N + iBase + lc];
        *(float4*)&Bs[lr][lc]   = *(const float4*)&Ab[(size_t)(k0 + lr) * N + jBase + lc];
        *(float4*)&Bs[lr+8][lc] = *(const float4*)&Ab[(size_t)(k0 + lr + 8) * N + jBase + lc];
        __syncthreads();
        #pragma unroll
        for (int k = 0; k < TK; ++k) {
            float4 a0 = *(float4*)&As[k][ty * 4];
            float4 a1 = *(float4*)&As[k][ty * 4 + 64];
            float4 b0 = *(float4*)&Bs[k][tx * 4];
            float4 b1 = *(float4*)&Bs[k][tx * 4 + 64];
            float av[2][4] = {{a0.x,a0.y,a0.z,a0.w},{a1.x,a1.y,a1.z,a1.w}};
            float bv[2][4] = {{b0.x,b0.y,b0.z,b0.w},{b1.x,b1.y,b1.z,b1.w}};
            #pragma unroll
            for (int iq = 0; iq < 2; ++iq)
                #pragma unroll
                for (int i = 0; i < 4; ++i)
                    #pragma unroll
                    for (int jq = 0; jq < 2; ++jq)
                        #pragma unroll
                        for (int j = 0; j < 4; ++j)
                            acc[iq][jq][i][j] += av[iq][i] * bv[jq][j];
        }
        __syncthreads();
    }

    float ss = 0.f;
    #pragma unroll
    for (int iq = 0; iq < 2; ++iq)
        #pragma unroll
        for (int i = 0; i < 4; ++i) {
            int row = iBase + iq * 64 + ty * 4 + i;
            #pragma unroll
            for (int jq = 0; jq < 2; ++jq) {
                float4 o;
                o.x = acc[iq][jq][i][0] * alpha;
                o.y = acc[iq][jq][i][1] * alpha;
                o.z = acc[iq][jq][i][2] * alpha;
                o.w = acc[iq][jq][i][3] * alpha;
                ss += o.x*o.x + o.y*o.y + o.z*o.z + o.w*o.w;
                *(float4*)&Cb[(size_t)row * N + jBase + jq * 64 + tx * 4] = o;
            }
        }

    if (fdst) {
        for (int o = 32; o; o >>= 1) ss += __shfl_down(ss, o, 64);
        __shared__ float red[4];
        int lane = t & 63, wv = t >> 6;
        if (lane == 0) red[wv] = ss;
        __syncthreads();
        if (t == 0) atomicAdd(&fdst[b], red[0] + red[1] + red[2] + red[3]);
    }
}

// ---------------- MFMA GEMM for SYMMETRIC input: C = alpha * A*A  ----------------
// fp32 emulated via 3-way bf16 split (hi/mid/lo, 6 MFMA products).
// Input A must be symmetric (true for all A^T A products). Panels staged k-contiguous
// by reading rows (= columns, by symmetry). 128x128 tile, 256 thr, K-step 32.
#define WS2 36   // padded k-stride (ushorts): 72 B -> 16 banks, b64-aligned

__device__ inline short8 ldfrag(const ushort* base, int p, int c, int q8) {
    const ushort* ptr = base + ((p * 128 + c) * WS2 + q8);
    ushort4 a = *(const ushort4*)ptr;
    ushort4 b = *(const ushort4*)(ptr + 4);
    short8 f;
    f[0] = (short)a.x; f[1] = (short)a.y; f[2] = (short)a.z; f[3] = (short)a.w;
    f[4] = (short)b.x; f[5] = (short)b.y; f[6] = (short)b.z; f[7] = (short)b.w;
    return f;
}

__device__ inline void split_store(ushort* base, int c, int kbase, const float* xv) {
    ushort h[16], m[16], l[16];
    #pragma unroll
    for (int i = 0; i < 16; ++i) {
        unsigned short hh = f2bf(xv[i]);
        float r = xv[i] - bf2f(hh);
        unsigned short mm = f2bf(r);
        float r2 = r - bf2f(mm);
        h[i] = hh; m[i] = mm; l[i] = f2bf(r2);
    }
    #pragma unroll
    for (int g = 0; g < 4; ++g) {
        *(ushort4*)&base[(0 * 128 + c) * WS2 + kbase + g * 4] = make_ushort4(h[g*4], h[g*4+1], h[g*4+2], h[g*4+3]);
        *(ushort4*)&base[(1 * 128 + c) * WS2 + kbase + g * 4] = make_ushort4(m[g*4], m[g*4+1], m[g*4+2], m[g*4+3]);
        *(ushort4*)&base[(2 * 128 + c) * WS2 + kbase + g * 4] = make_ushort4(l[g*4], l[g*4+1], l[g*4+2], l[g*4+3]);
    }
}

__global__ __launch_bounds__(256, 2) void k_gemm_mfma(const float* __restrict__ A, float* __restrict__ C,
                                                      const float* __restrict__ fsrc, float* __restrict__ fdst) {
    int b = blockIdx.z;
    const float* Ab = A + (size_t)b * MAT;
    float* Cb = C + (size_t)b * MAT;

    __shared__ ushort sI[3 * 128 * WS2];
    __shared__ ushort sJ[3 * 128 * WS2];

    int t = threadIdx.x;
    int iBase = blockIdx.y * 128, jBase = blockIdx.x * 128;
    bool diag = (iBase == jBase);
    const ushort* Jb = diag ? sI : sJ;

    int lane = t & 63, wv = t >> 6;
    int wi = wv >> 1, wj = wv & 1;
    int cc = lane & 15, cq = lane >> 4;   // col-in-tile, quad
    int q8 = cq * 8;

    int sc = t & 127;          // staged row (panel-local)
    int kh = t >> 7;           // 0..1 -> k-halves of 16

    float alpha = fsrc ? (1.0f / fsrc[b]) : 1.0f;

    f32x4 acc[4][4];
    #pragma unroll
    for (int i = 0; i < 4; ++i)
        #pragma unroll
        for (int j = 0; j < 4; ++j)
            acc[i][j] = (f32x4)0.f;

    for (int k0 = 0; k0 < N; k0 += 32) {
        // ---- stage panels (rows = cols via symmetry; k-contiguous) ----
        float xv[16];
        const float* rowI = Ab + (size_t)(iBase + sc) * N + k0 + kh * 16;
        *(float4*)&xv[0]  = *(const float4*)&rowI[0];
        *(float4*)&xv[4]  = *(const float4*)&rowI[4];
        *(float4*)&xv[8]  = *(const float4*)&rowI[8];
        *(float4*)&xv[12] = *(const float4*)&rowI[12];
        split_store(sI, sc, kh * 16, xv);
        if (!diag) {
            const float* rowJ = Ab + (size_t)(jBase + sc) * N + k0 + kh * 16;
            *(float4*)&xv[0]  = *(const float4*)&rowJ[0];
            *(float4*)&xv[4]  = *(const float4*)&rowJ[4];
            *(float4*)&xv[8]  = *(const float4*)&rowJ[8];
            *(float4*)&xv[12] = *(const float4*)&rowJ[12];
            split_store(sJ, sc, kh * 16, xv);
        }
        __syncthreads();

        // ---- B fragments: 4 col-tiles x 3 planes ----
        short8 bf[4][3];
        #pragma unroll
        for (int ct = 0; ct < 4; ++ct)
            #pragma unroll
            for (int p = 0; p < 3; ++p)
                bf[ct][p] = ldfrag(Jb, p, wj * 64 + ct * 16 + cc, q8);

        #pragma unroll
        for (int rt = 0; rt < 4; ++rt) {
            short8 af0 = ldfrag(sI, 0, wi * 64 + rt * 16 + cc, q8);
            short8 af1 = ldfrag(sI, 1, wi * 64 + rt * 16 + cc, q8);
            short8 af2 = ldfrag(sI, 2, wi * 64 + rt * 16 + cc, q8);
            #pragma unroll
            for (int ct = 0; ct < 4; ++ct) {
                f32x4 a = acc[rt][ct];
                a = __builtin_amdgcn_mfma_f32_16x16x32_bf16(af0, bf[ct][0], a, 0, 0, 0); // hh
                a = __builtin_amdgcn_mfma_f32_16x16x32_bf16(af0, bf[ct][1], a, 0, 0, 0); // hm
                a = __builtin_amdgcn_mfma_f32_16x16x32_bf16(af1, bf[ct][0], a, 0, 0, 0); // mh
                a = __builtin_amdgcn_mfma_f32_16x16x32_bf16(af1, bf[ct][1], a, 0, 0, 0); // mm
                a = __builtin_amdgcn_mfma_f32_16x16x32_bf16(af0, bf[ct][2], a, 0, 0, 0); // hl
                a = __builtin_amdgcn_mfma_f32_16x16x32_bf16(af2, bf[ct][0], a, 0, 0, 0); // lh
                acc[rt][ct] = a;
            }
        }
        __syncthreads();
    }

    // ---- epilogue: scale, write, frobenius ----
    float ss = 0.f;
    #pragma unroll
    for (int rt = 0; rt < 4; ++rt) {
        int i0 = iBase + wi * 64 + rt * 16 + cq * 4;
        #pragma unroll
        for (int ct = 0; ct < 4; ++ct) {
            int j0 = jBase + wj * 64 + ct * 16 + cc;
            #pragma unroll
            for (int r = 0; r < 4; ++r) {
                float o = acc[rt][ct][r] * alpha;
                ss += o * o;
                Cb[(size_t)(i0 + r) * N + j0] = o;
            }
        }
    }

    if (fdst) {
        for (int o = 32; o; o >>= 1) ss += __shfl_down(ss, o, 64);
        __shared__ float red[4];
        if (lane == 0) red[wv] = ss;
        __syncthreads();
        if (t == 0) atomicAdd(&fdst[b], red[0] + red[1] + red[2] + red[3]);
    }
}

// ---------------- power iteration on symmetric Cm (=B^256), then w = Y v ----------------
__global__ __launch_bounds__(512) void k_power(const float* __restrict__ Cm, const float* __restrict__ Y,
                                               float* __restrict__ vout, float* __restrict__ wout, int iters) {
    int b = blockIdx.x;
    const float* C = Cm + (size_t)b * MAT;
    const float* Yb = Y + (size_t)b * MAT;
    __shared__ __align__(16) float va[N];
    __shared__ __align__(16) float vb[N];
    __shared__ float red[8];
    __shared__ float snorm;
    int t = threadIdx.x, lane = t & 63, wv = t >> 6;

    unsigned h = (unsigned)t * 1103515245u + 12345u;
    va[t] = (float)((h >> 16) & 0x7fff) / 16384.f - 1.f;
    __syncthreads();

    const float* Ct = C + t;
    for (int it = 0; it < iters; ++it) {
        float* src = (it & 1) ? vb : va;
        float* dst = (it & 1) ? va : vb;
        float acc = 0.f;
        #pragma unroll 4
        for (int c = 0; c < N; c += 8) {
            float4 s0 = *(const float4*)&src[c];
            float4 s1 = *(const float4*)&src[c + 4];
            const float* p = Ct + (size_t)c * N;
            acc += p[0 * N] * s0.x;
            acc += p[1 * N] * s0.y;
            acc += p[2 * N] * s0.z;
            acc += p[3 * N] * s0.w;
            acc += p[4 * N] * s1.x;
            acc += p[5 * N] * s1.y;
            acc += p[6 * N] * s1.z;
            acc += p[7 * N] * s1.w;
        }
        dst[t] = acc;
        __syncthreads();
    }

    float* fin = (iters & 1) ? vb : va;
    float* oth = (iters & 1) ? va : vb;
    float val = fin[t];
    float ss = val * val;
    for (int o = 32; o; o >>= 1) ss += __shfl_xor(ss, o, 64);
    if (lane == 0) red[wv] = ss;
    __syncthreads();
    if (t == 0) {
        float tt = 0.f;
        #pragma unroll
        for (int i = 0; i < 8; ++i) tt += red[i];
        snorm = rsqrtf(tt);
    }
    __syncthreads();
    fin[t] = val * snorm;
    __syncthreads();

    int rbase = wv * 64;
    for (int g = 0; g < 8; ++g) {
        float accw[8] = {0,0,0,0,0,0,0,0};
        #pragma unroll
        for (int c = 0; c < 8; ++c) {
            float vvl = fin[c * 64 + lane];
            #pragma unroll
            for (int q = 0; q < 8; ++q)
                accw[q] += Yb[(size_t)(rbase + g * 8 + q) * N + c * 64 + lane] * vvl;
        }
        #pragma unroll
        for (int q = 0; q < 8; ++q) {
            float s = accw[q];
            for (int o = 32; o; o >>= 1) s += __shfl_xor(s, o, 64);
            if (lane == 0) oth[rbase + g * 8 + q] = s;
        }
    }
    __syncthreads();
    vout[(size_t)b * N + t] = fin[t];
    wout[(size_t)b * N + t] = oth[t];
}

// ---------------- out[b,i,j] = w[b,i] * v[b,j] ----------------
__global__ __launch_bounds__(256) void k_outer(const float* __restrict__ v, const float* __restrict__ w,
                                               float* __restrict__ out) {
    int tid = blockIdx.x * 256 + threadIdx.x;
    int b = tid >> 16;
    int rem = tid & 65535;
    int i = rem >> 7;
    int j4 = rem & 127;
    float wi = w[(size_t)b * N + i];
    float4 vv = ((const float4*)(v + (size_t)b * N))[j4];
    float4 o = {wi * vv.x, wi * vv.y, wi * vv.z, wi * vv.w};
    ((float4*)out)[tid] = o;
}

extern "C" void kernel_launch(void* const* d_in, const int* in_sizes, int n_in,
                              void* d_out, int out_size, void* d_ws, size_t ws_size,
                              hipStream_t stream) {
    const float* x = (const float*)d_in[0];
    float* out = (float*)d_out;
    float* f = (float*)d_ws;

    float* Ba = f;                                // 32 MB
    float* Bb = f + (size_t)NB * MAT;             // 32 MB
    float* fs = f + (size_t)2 * NB * MAT;         // 8*32 floats frob2 accumulators
    float* vv = fs + 8 * 32;
    float* ww = vv + (size_t)NB * N;
    float* y  = out;                              // stage luma in d_out

    hipMemsetAsync(fs, 0, 8 * 32 * sizeof(float), stream);
    k_luma<<<8192, 256, 0, stream>>>(x, y);

    dim3 gg(N / 128, N / 128, NB);   // 4 x 4 x 32
    k_gemm_f32 <<<gg, 256, 0, stream>>>(y,  Ba, nullptr,   fs + 0*32);  // B       (fp32: y not symmetric)
    k_gemm_mfma<<<gg, 256, 0, stream>>>(Ba, Bb, fs + 0*32, fs + 1*32);  // B^2
    k_gemm_mfma<<<gg, 256, 0, stream>>>(Bb, Ba, fs + 1*32, fs + 2*32);  // B^4
    k_gemm_mfma<<<gg, 256, 0, stream>>>(Ba, Bb, fs + 2*32, fs + 3*32);  // B^8
    k_gemm_mfma<<<gg, 256, 0, stream>>>(Bb, Ba, fs + 3*32, fs + 4*32);  // B^16
    k_gemm_mfma<<<gg, 256, 0, stream>>>(Ba, Bb, fs + 4*32, fs + 5*32);  // B^32
    k_gemm_mfma<<<gg, 256, 0, stream>>>(Bb, Ba, fs + 5*32, fs + 6*32);  // B^64
    k_gemm_mfma<<<gg, 256, 0, stream>>>(Ba, Bb, fs + 6*32, fs + 7*32);  // B^128
    k_gemm_mfma<<<gg, 256, 0, stream>>>(Bb, Ba, fs + 7*32, nullptr);    // B^256 -> Ba

    k_power<<<NB, 512, 0, stream>>>(Ba, y, vv, ww, 12);
    k_outer<<<8192, 256, 0, stream>>>(vv, ww, out);
}

// Round 4
// 695.142 us; speedup vs baseline: 4.9252x; 1.3441x over previous
//
#include <hip/hip_runtime.h>
#include <hip/hip_fp16.h>

#define NB 32
#define N 512
#define MAT (N*N)   // 262144

typedef _Float16 half8 __attribute__((ext_vector_type(8)));
typedef float f32x4 __attribute__((ext_vector_type(4)));

#define MSCALE 2048.0f
#define RMSCALE (1.0f/2048.0f)

// split x into fp16 h + fp16 m' where x ~= h + m' * 2^-11 (m' scaled to avoid denormals)
__device__ inline ushort2 split2(float x) {
    __half h = __float2half(x);
    __half m = __float2half((x - __half2float(h)) * MSCALE);
    return make_ushort2(__half_as_ushort(h), __half_as_ushort(m));
}

// async global->LDS DMA, 16B per lane; LDS dest = wave-uniform base + lane*16
__device__ inline void gload(const ushort* g, ushort* l) {
    __builtin_amdgcn_global_load_lds((const __attribute__((address_space(1))) void*)g,
                                     (__attribute__((address_space(3))) void*)l, 16, 0, 0);
}

// ---------------- luma + transpose: yT fp32 + yT fp16 planes ----------------
// grid: (64 tiles of 64x64, NB batches), 256 threads
__global__ __launch_bounds__(256) void k_luma(const float* __restrict__ x, float* __restrict__ yT,
                                              ushort* __restrict__ Ph, ushort* __restrict__ Pm) {
    int b = blockIdx.y;
    int tile = blockIdx.x;
    int TR = (tile >> 3) * 64;   // row base in y
    int TC = (tile & 7) * 64;    // col base in y
    __shared__ float ld[64][65];
    int t = threadIdx.x;
    int r0 = t >> 4;             // 0..15
    int c4 = (t & 15) * 4;       // 0..60
    const float* xb = x + (size_t)b * 3 * MAT;
    #pragma unroll
    for (int q = 0; q < 4; ++q) {
        int row = r0 + q * 16;
        size_t off = (size_t)(TR + row) * N + TC + c4;
        float4 rr = *(const float4*)&xb[off];
        float4 gg = *(const float4*)&xb[off + MAT];
        float4 bb = *(const float4*)&xb[off + 2 * MAT];
        ld[row][c4 + 0] = 0.299f * rr.x + 0.587f * gg.x + 0.114f * bb.x;
        ld[row][c4 + 1] = 0.299f * rr.y + 0.587f * gg.y + 0.114f * bb.y;
        ld[row][c4 + 2] = 0.299f * rr.z + 0.587f * gg.z + 0.114f * bb.z;
        ld[row][c4 + 3] = 0.299f * rr.w + 0.587f * gg.w + 0.114f * bb.w;
    }
    __syncthreads();
    float* yTb = yT + (size_t)b * MAT;
    ushort* PhB = Ph + (size_t)b * MAT;
    ushort* PmB = Pm + (size_t)b * MAT;
    #pragma unroll
    for (int q = 0; q < 4; ++q) {
        int i = r0 + q * 16;     // row of yT tile
        float v0 = ld[c4 + 0][i];
        float v1 = ld[c4 + 1][i];
        float v2 = ld[c4 + 2][i];
        float v3 = ld[c4 + 3][i];
        size_t off = (size_t)(TC + i) * N + TR + c4;
        *(float4*)&yTb[off] = make_float4(v0, v1, v2, v3);
        ushort2 s0 = split2(v0), s1 = split2(v1), s2 = split2(v2), s3 = split2(v3);
        *(ushort4*)&PhB[off] = make_ushort4(s0.x, s1.x, s2.x, s3.x);
        *(ushort4*)&PmB[off] = make_ushort4(s0.y, s1.y, s2.y, s3.y);
    }
}

// ---------------- MFMA GEMM: C = alpha * P * P^T from fp16 planes ----------------
// 128x128 tile, 256 thr, K-step 32. Output: fp16 planes (Qh,Qm) or fp32 (Cf).
__global__ __launch_bounds__(256, 2) void k_gemm(const ushort* __restrict__ Ph, const ushort* __restrict__ Pm,
                                                 ushort* __restrict__ Qh, ushort* __restrict__ Qm,
                                                 float* __restrict__ Cf,
                                                 const float* __restrict__ fsrc, float* __restrict__ fdst) {
    int b = blockIdx.z;
    const ushort* PhB = Ph + (size_t)b * MAT;
    const ushort* PmB = Pm + (size_t)b * MAT;

    __shared__ __align__(16) ushort sI[2][128 * 32];
    __shared__ __align__(16) ushort sJ[2][128 * 32];

    int t = threadIdx.x;
    int iBase = blockIdx.y * 128, jBase = blockIdx.x * 128;
    bool diag = (iBase == jBase);

    int lane = t & 63, wv = t >> 6;
    int wi = wv >> 1, wj = wv & 1;
    int cc = lane & 15, cq = lane >> 4;
    int q8 = cq * 8;
    int lrow = lane >> 2;    // row-in-chunk
    int lseg = lane & 3;     // 16B segment

    float alpha = fsrc ? (1.0f / fsrc[b]) : 1.0f;

    f32x4 acc0[4][4], acc1[4][4];
    #pragma unroll
    for (int i = 0; i < 4; ++i)
        #pragma unroll
        for (int j = 0; j < 4; ++j) { acc0[i][j] = (f32x4)0.f; acc1[i][j] = (f32x4)0.f; }

    for (int k0 = 0; k0 < N; k0 += 32) {
        if (diag) {
            #pragma unroll
            for (int j = 0; j < 4; ++j) {
                int q = wv * 4 + j;
                int pl = q >> 3, rg = q & 7;
                const ushort* src = (pl ? PmB : PhB) + (size_t)(iBase + rg * 16 + lrow) * N + k0 + lseg * 8;
                gload(src, &sI[pl][rg * 512]);
            }
        } else {
            #pragma unroll
            for (int j = 0; j < 8; ++j) {
                int q = wv * 8 + j;
                int panel = q >> 4, pl = (q >> 3) & 1, rg = q & 7;
                int rb = panel ? jBase : iBase;
                const ushort* src = (pl ? PmB : PhB) + (size_t)(rb + rg * 16 + lrow) * N + k0 + lseg * 8;
                gload(src, panel ? &sJ[pl][rg * 512] : &sI[pl][rg * 512]);
            }
        }
        __syncthreads();

        const ushort(*Jb)[128 * 32] = diag ? sI : sJ;

        half8 bh[4], bm[4];
        #pragma unroll
        for (int ct = 0; ct < 4; ++ct) {
            int row = wj * 64 + ct * 16 + cc;
            bh[ct] = *(const half8*)&Jb[0][row * 32 + q8];
            bm[ct] = *(const half8*)&Jb[1][row * 32 + q8];
        }
        #pragma unroll
        for (int rt = 0; rt < 4; ++rt) {
            int row = wi * 64 + rt * 16 + cc;
            half8 ah = *(const half8*)&sI[0][row * 32 + q8];
            half8 am = *(const half8*)&sI[1][row * 32 + q8];
            #pragma unroll
            for (int ct = 0; ct < 4; ++ct) {
                acc0[rt][ct] = __builtin_amdgcn_mfma_f32_16x16x32_f16(ah, bh[ct], acc0[rt][ct], 0, 0, 0);
                acc1[rt][ct] = __builtin_amdgcn_mfma_f32_16x16x32_f16(ah, bm[ct], acc1[rt][ct], 0, 0, 0);
                acc1[rt][ct] = __builtin_amdgcn_mfma_f32_16x16x32_f16(am, bh[ct], acc1[rt][ct], 0, 0, 0);
            }
        }
        __syncthreads();
    }

    // epilogue: reconstruct, scale, emit planes or fp32, frobenius
    ushort* QhB = Qh ? Qh + (size_t)b * MAT : nullptr;
    ushort* QmB = Qm ? Qm + (size_t)b * MAT : nullptr;
    float* CfB = Cf ? Cf + (size_t)b * MAT : nullptr;
    float ss = 0.f;
    #pragma unroll
    for (int rt = 0; rt < 4; ++rt) {
        int i0 = iBase + wi * 64 + rt * 16 + cq * 4;
        #pragma unroll
        for (int ct = 0; ct < 4; ++ct) {
            int j0 = jBase + wj * 64 + ct * 16 + cc;
            #pragma unroll
            for (int r = 0; r < 4; ++r) {
                float o = (acc0[rt][ct][r] + acc1[rt][ct][r] * RMSCALE) * alpha;
                ss += o * o;
                size_t idx = (size_t)(i0 + r) * N + j0;
                if (CfB) {
                    CfB[idx] = o;
                } else {
                    ushort2 hm = split2(o);
                    QhB[idx] = hm.x;
                    QmB[idx] = hm.y;
                }
            }
        }
    }

    if (fdst) {
        for (int o = 32; o; o >>= 1) ss += __shfl_down(ss, o, 64);
        __shared__ float red[4];
        if (lane == 0) red[wv] = ss;
        __syncthreads();
        if (t == 0) atomicAdd(&fdst[b], red[0] + red[1] + red[2] + red[3]);
    }
}

// ---------------- power iteration on symmetric C (=B^512), then w via yT ----------------
__global__ __launch_bounds__(512) void k_power(const float* __restrict__ Cm, const float* __restrict__ YT,
                                               float* __restrict__ vout, float* __restrict__ wout, int iters) {
    int b = blockIdx.x;
    const float* C = Cm + (size_t)b * MAT;
    const float* Yt = YT + (size_t)b * MAT;
    __shared__ __align__(16) float va[N];
    __shared__ __align__(16) float vb[N];
    __shared__ float red[8];
    __shared__ float snorm;
    int t = threadIdx.x, lane = t & 63, wv = t >> 6;

    unsigned h = (unsigned)t * 1103515245u + 12345u;
    va[t] = (float)((h >> 16) & 0x7fff) / 16384.f - 1.f;
    __syncthreads();

    const float* Ct = C + t;
    for (int it = 0; it < iters; ++it) {
        float* src = (it & 1) ? vb : va;
        float* dst = (it & 1) ? va : vb;
        float acc = 0.f;
        #pragma unroll 4
        for (int c = 0; c < N; c += 8) {
            float4 s0 = *(const float4*)&src[c];
            float4 s1 = *(const float4*)&src[c + 4];
            const float* p = Ct + (size_t)c * N;
            acc += p[0 * N] * s0.x;
            acc += p[1 * N] * s0.y;
            acc += p[2 * N] * s0.z;
            acc += p[3 * N] * s0.w;
            acc += p[4 * N] * s1.x;
            acc += p[5 * N] * s1.y;
            acc += p[6 * N] * s1.z;
            acc += p[7 * N] * s1.w;
        }
        dst[t] = acc;
        __syncthreads();
    }

    float* fin = (iters & 1) ? vb : va;
    float val = fin[t];
    float ss = val * val;
    for (int o = 32; o; o >>= 1) ss += __shfl_xor(ss, o, 64);
    if (lane == 0) red[wv] = ss;
    __syncthreads();
    if (t == 0) {
        float tt = 0.f;
        #pragma unroll
        for (int i = 0; i < 8; ++i) tt += red[i];
        snorm = rsqrtf(tt);
    }
    __syncthreads();
    fin[t] = val * snorm;
    __syncthreads();

    // w[t] = sum_c Y[t][c] v[c] = sum_c yT[c][t] v[c]  (coalesced)
    const float* Ytt = Yt + t;
    float accw = 0.f;
    #pragma unroll 4
    for (int c = 0; c < N; c += 8) {
        float4 s0 = *(const float4*)&fin[c];
        float4 s1 = *(const float4*)&fin[c + 4];
        const float* p = Ytt + (size_t)c * N;
        accw += p[0 * N] * s0.x;
        accw += p[1 * N] * s0.y;
        accw += p[2 * N] * s0.z;
        accw += p[3 * N] * s0.w;
        accw += p[4 * N] * s1.x;
        accw += p[5 * N] * s1.y;
        accw += p[6 * N] * s1.z;
        accw += p[7 * N] * s1.w;
    }
    vout[(size_t)b * N + t] = fin[t];
    wout[(size_t)b * N + t] = accw;
}

// ---------------- out[b,i,j] = w[b,i] * v[b,j] ----------------
__global__ __launch_bounds__(256) void k_outer(const float* __restrict__ v, const float* __restrict__ w,
                                               float* __restrict__ out) {
    int tid = blockIdx.x * 256 + threadIdx.x;
    int b = tid >> 16;
    int rem = tid & 65535;
    int i = rem >> 7;
    int j4 = rem & 127;
    float wi = w[(size_t)b * N + i];
    float4 vv = ((const float4*)(v + (size_t)b * N))[j4];
    float4 o = {wi * vv.x, wi * vv.y, wi * vv.z, wi * vv.w};
    ((float4*)out)[tid] = o;
}

extern "C" void kernel_launch(void* const* d_in, const int* in_sizes, int n_in,
                              void* d_out, int out_size, void* d_ws, size_t ws_size,
                              hipStream_t stream) {
    const float* x = (const float*)d_in[0];
    float* out = (float*)d_out;
    char* base = (char*)d_ws;

    const size_t PL = (size_t)NB * MAT * sizeof(ushort);   // 16 MB per plane array
    ushort* AH = (ushort*)(base);
    ushort* AM = (ushort*)(base + PL);
    ushort* BH = (ushort*)(base + 2 * PL);
    ushort* BM = (ushort*)(base + 3 * PL);
    float*  Cf = (float*)(base);                 // aliases A region; last GEMM reads B, writes here
    float*  fs = (float*)(base + 4 * PL);        // frob2 accumulators
    float*  vv = fs + 512;
    float*  ww = vv + (size_t)NB * N;
    float*  yT = out;                            // stage yT fp32 in d_out

    hipMemsetAsync(fs, 0, 512 * sizeof(float), stream);
    k_luma<<<dim3(64, NB), 256, 0, stream>>>(x, yT, AH, AM);

    dim3 gg(4, 4, NB);
    k_gemm<<<gg, 256, 0, stream>>>(AH, AM, BH, BM, nullptr, nullptr,  fs + 0 * 32); // B = yT yT^T
    k_gemm<<<gg, 256, 0, stream>>>(BH, BM, AH, AM, nullptr, fs + 0*32, fs + 1 * 32); // B^2
    k_gemm<<<gg, 256, 0, stream>>>(AH, AM, BH, BM, nullptr, fs + 1*32, fs + 2 * 32); // B^4
    k_gemm<<<gg, 256, 0, stream>>>(BH, BM, AH, AM, nullptr, fs + 2*32, fs + 3 * 32); // B^8
    k_gemm<<<gg, 256, 0, stream>>>(AH, AM, BH, BM, nullptr, fs + 3*32, fs + 4 * 32); // B^16
    k_gemm<<<gg, 256, 0, stream>>>(BH, BM, AH, AM, nullptr, fs + 4*32, fs + 5 * 32); // B^32
    k_gemm<<<gg, 256, 0, stream>>>(AH, AM, BH, BM, nullptr, fs + 5*32, fs + 6 * 32); // B^64
    k_gemm<<<gg, 256, 0, stream>>>(BH, BM, AH, AM, nullptr, fs + 6*32, fs + 7 * 32); // B^128
    k_gemm<<<gg, 256, 0, stream>>>(AH, AM, BH, BM, nullptr, fs + 7*32, fs + 8 * 32); // B^256 -> B bufs
    k_gemm<<<gg, 256, 0, stream>>>(BH, BM, nullptr, nullptr, Cf, fs + 8*32, nullptr); // B^512 fp32 -> Cf

    k_power<<<NB, 512, 0, stream>>>(Cf, yT, vv, ww, 6);
    k_outer<<<8192, 256, 0, stream>>>(vv, ww, out);
}

// Round 5
// 521.138 us; speedup vs baseline: 6.5697x; 1.3339x over previous
//
#include <hip/hip_runtime.h>
#include <hip/hip_fp16.h>

#define NB 32
#define N 512
#define MAT (N*N)   // 262144

typedef _Float16 half8 __attribute__((ext_vector_type(8)));
typedef float f32x4 __attribute__((ext_vector_type(4)));

#define MSCALE 2048.0f
#define RMSCALE (1.0f/2048.0f)

// split x into fp16 h + fp16 m' where x ~= h + m' * 2^-11 (m' scaled to avoid denormals)
__device__ inline ushort2 split2(float x) {
    __half h = __float2half(x);
    __half m = __float2half((x - __half2float(h)) * MSCALE);
    return make_ushort2(__half_as_ushort(h), __half_as_ushort(m));
}

// async global->LDS DMA, 16B per lane; LDS dest = wave-uniform base + lane*16
__device__ inline void gload(const ushort* g, ushort* l) {
    __builtin_amdgcn_global_load_lds((const __attribute__((address_space(1))) void*)g,
                                     (__attribute__((address_space(3))) void*)l, 16, 0, 0);
}

// ---------------- luma + transpose: yT fp32 + yT fp16 planes ----------------
__global__ __launch_bounds__(256) void k_luma(const float* __restrict__ x, float* __restrict__ yT,
                                              ushort* __restrict__ Ph, ushort* __restrict__ Pm) {
    int b = blockIdx.y;
    int tile = blockIdx.x;
    int TR = (tile >> 3) * 64;
    int TC = (tile & 7) * 64;
    __shared__ float ld[64][65];
    int t = threadIdx.x;
    int r0 = t >> 4;
    int c4 = (t & 15) * 4;
    const float* xb = x + (size_t)b * 3 * MAT;
    #pragma unroll
    for (int q = 0; q < 4; ++q) {
        int row = r0 + q * 16;
        size_t off = (size_t)(TR + row) * N + TC + c4;
        float4 rr = *(const float4*)&xb[off];
        float4 gg = *(const float4*)&xb[off + MAT];
        float4 bb = *(const float4*)&xb[off + 2 * MAT];
        ld[row][c4 + 0] = 0.299f * rr.x + 0.587f * gg.x + 0.114f * bb.x;
        ld[row][c4 + 1] = 0.299f * rr.y + 0.587f * gg.y + 0.114f * bb.y;
        ld[row][c4 + 2] = 0.299f * rr.z + 0.587f * gg.z + 0.114f * bb.z;
        ld[row][c4 + 3] = 0.299f * rr.w + 0.587f * gg.w + 0.114f * bb.w;
    }
    __syncthreads();
    float* yTb = yT + (size_t)b * MAT;
    ushort* PhB = Ph + (size_t)b * MAT;
    ushort* PmB = Pm + (size_t)b * MAT;
    #pragma unroll
    for (int q = 0; q < 4; ++q) {
        int i = r0 + q * 16;
        float v0 = ld[c4 + 0][i];
        float v1 = ld[c4 + 1][i];
        float v2 = ld[c4 + 2][i];
        float v3 = ld[c4 + 3][i];
        size_t off = (size_t)(TC + i) * N + TR + c4;
        *(float4*)&yTb[off] = make_float4(v0, v1, v2, v3);
        ushort2 s0 = split2(v0), s1 = split2(v1), s2 = split2(v2), s3 = split2(v3);
        *(ushort4*)&PhB[off] = make_ushort4(s0.x, s1.x, s2.x, s3.x);
        *(ushort4*)&PmB[off] = make_ushort4(s0.y, s1.y, s2.y, s3.y);
    }
}

// ---------------- MFMA GEMM: C = alpha * P * P^T from fp16 planes ----------------
// NPIN=2: hi+mid planes, 3 MFMA products. NPIN=1: h plane only, 1 product.
// Output planes: Qh always, Qm only if non-null.
template<int NPIN>
__global__ __launch_bounds__(256, 2) void k_gemm(const ushort* __restrict__ Ph, const ushort* __restrict__ Pm,
                                                 ushort* __restrict__ Qh, ushort* __restrict__ Qm,
                                                 const float* __restrict__ fsrc, float* __restrict__ fdst) {
    int b = blockIdx.z;
    const ushort* PhB = Ph + (size_t)b * MAT;
    const ushort* PmB = (NPIN == 2) ? Pm + (size_t)b * MAT : nullptr;

    __shared__ __align__(16) ushort sI[NPIN][128 * 32];
    __shared__ __align__(16) ushort sJ[NPIN][128 * 32];

    int t = threadIdx.x;
    int iBase = blockIdx.y * 128, jBase = blockIdx.x * 128;
    bool diag = (iBase == jBase);

    int lane = t & 63, wv = t >> 6;
    int wi = wv >> 1, wj = wv & 1;
    int cc = lane & 15, cq = lane >> 4;
    int q8 = cq * 8;
    int lrow = lane >> 2;
    int lseg = lane & 3;

    float alpha = fsrc ? (1.0f / fsrc[b]) : 1.0f;

    f32x4 acc0[4][4], acc1[4][4];
    #pragma unroll
    for (int i = 0; i < 4; ++i)
        #pragma unroll
        for (int j = 0; j < 4; ++j) { acc0[i][j] = (f32x4)0.f; acc1[i][j] = (f32x4)0.f; }

    for (int k0 = 0; k0 < N; k0 += 32) {
        if (NPIN == 2) {
            if (diag) {
                #pragma unroll
                for (int j = 0; j < 4; ++j) {
                    int q = wv * 4 + j;
                    int pl = q >> 3, rg = q & 7;
                    const ushort* src = (pl ? PmB : PhB) + (size_t)(iBase + rg * 16 + lrow) * N + k0 + lseg * 8;
                    gload(src, &sI[pl][rg * 512]);
                }
            } else {
                #pragma unroll
                for (int j = 0; j < 8; ++j) {
                    int q = wv * 8 + j;
                    int panel = q >> 4, pl = (q >> 3) & 1, rg = q & 7;
                    int rb = panel ? jBase : iBase;
                    const ushort* src = (pl ? PmB : PhB) + (size_t)(rb + rg * 16 + lrow) * N + k0 + lseg * 8;
                    gload(src, panel ? &sJ[pl][rg * 512] : &sI[pl][rg * 512]);
                }
            }
        } else {
            if (diag) {
                #pragma unroll
                for (int j = 0; j < 2; ++j) {
                    int rg = wv * 2 + j;
                    const ushort* src = PhB + (size_t)(iBase + rg * 16 + lrow) * N + k0 + lseg * 8;
                    gload(src, &sI[0][rg * 512]);
                }
            } else {
                #pragma unroll
                for (int j = 0; j < 4; ++j) {
                    int q = wv * 4 + j;
                    int panel = q >> 3, rg = q & 7;
                    int rb = panel ? jBase : iBase;
                    const ushort* src = PhB + (size_t)(rb + rg * 16 + lrow) * N + k0 + lseg * 8;
                    gload(src, panel ? &sJ[0][rg * 512] : &sI[0][rg * 512]);
                }
            }
        }
        __syncthreads();

        const ushort(*Jb)[128 * 32] = diag ? sI : sJ;

        half8 bh[4], bm[4];
        #pragma unroll
        for (int ct = 0; ct < 4; ++ct) {
            int row = wj * 64 + ct * 16 + cc;
            bh[ct] = *(const half8*)&Jb[0][row * 32 + q8];
            if (NPIN == 2) bm[ct] = *(const half8*)&Jb[1][row * 32 + q8];
        }
        #pragma unroll
        for (int rt = 0; rt < 4; ++rt) {
            int row = wi * 64 + rt * 16 + cc;
            half8 ah = *(const half8*)&sI[0][row * 32 + q8];
            half8 am;
            if (NPIN == 2) am = *(const half8*)&sI[1][row * 32 + q8];
            #pragma unroll
            for (int ct = 0; ct < 4; ++ct) {
                acc0[rt][ct] = __builtin_amdgcn_mfma_f32_16x16x32_f16(ah, bh[ct], acc0[rt][ct], 0, 0, 0);
                if (NPIN == 2) {
                    acc1[rt][ct] = __builtin_amdgcn_mfma_f32_16x16x32_f16(ah, bm[ct], acc1[rt][ct], 0, 0, 0);
                    acc1[rt][ct] = __builtin_amdgcn_mfma_f32_16x16x32_f16(am, bh[ct], acc1[rt][ct], 0, 0, 0);
                }
            }
        }
        __syncthreads();
    }

    ushort* QhB = Qh + (size_t)b * MAT;
    ushort* QmB = Qm ? Qm + (size_t)b * MAT : nullptr;
    float ss = 0.f;
    #pragma unroll
    for (int rt = 0; rt < 4; ++rt) {
        int i0 = iBase + wi * 64 + rt * 16 + cq * 4;
        #pragma unroll
        for (int ct = 0; ct < 4; ++ct) {
            int j0 = jBase + wj * 64 + ct * 16 + cc;
            #pragma unroll
            for (int r = 0; r < 4; ++r) {
                float o = acc0[rt][ct][r];
                if (NPIN == 2) o += acc1[rt][ct][r] * RMSCALE;
                o *= alpha;
                ss += o * o;
                size_t idx = (size_t)(i0 + r) * N + j0;
                if (QmB) {
                    ushort2 hm = split2(o);
                    QhB[idx] = hm.x;
                    QmB[idx] = hm.y;
                } else {
                    QhB[idx] = __half_as_ushort(__float2half(o));
                }
            }
        }
    }

    if (fdst) {
        for (int o = 32; o; o >>= 1) ss += __shfl_down(ss, o, 64);
        __shared__ float red[4];
        if (lane == 0) red[wv] = ss;
        __syncthreads();
        if (t == 0) atomicAdd(&fdst[b], red[0] + red[1] + red[2] + red[3]);
    }
}

// ---------------- power iteration on symmetric fp16 C (=B^256), then w via yT ----------------
__global__ __launch_bounds__(512) void k_power(const ushort* __restrict__ Ch, const float* __restrict__ YT,
                                               float* __restrict__ vout, float* __restrict__ wout, int iters) {
    int b = blockIdx.x;
    const __half* C = (const __half*)(Ch + (size_t)b * MAT);
    const float* Yt = YT + (size_t)b * MAT;
    __shared__ __align__(16) float va[N];
    __shared__ __align__(16) float vb[N];
    __shared__ float red[8];
    __shared__ float snorm;
    int t = threadIdx.x, lane = t & 63, wv = t >> 6;

    unsigned h = (unsigned)t * 1103515245u + 12345u;
    va[t] = (float)((h >> 16) & 0x7fff) / 16384.f - 1.f;
    __syncthreads();

    const __half* Ct = C + t;
    for (int it = 0; it < iters; ++it) {
        float* src = (it & 1) ? vb : va;
        float* dst = (it & 1) ? va : vb;
        float acc = 0.f;
        #pragma unroll 4
        for (int c = 0; c < N; c += 8) {
            float4 s0 = *(const float4*)&src[c];
            float4 s1 = *(const float4*)&src[c + 4];
            const __half* p = Ct + (size_t)c * N;
            acc += __half2float(p[0 * N]) * s0.x;
            acc += __half2float(p[1 * N]) * s0.y;
            acc += __half2float(p[2 * N]) * s0.z;
            acc += __half2float(p[3 * N]) * s0.w;
            acc += __half2float(p[4 * N]) * s1.x;
            acc += __half2float(p[5 * N]) * s1.y;
            acc += __half2float(p[6 * N]) * s1.z;
            acc += __half2float(p[7 * N]) * s1.w;
        }
        // renormalize each iter (fp16 matrix scale ~1, keep amplitudes sane)
        float ss = acc * acc;
        for (int o = 32; o; o >>= 1) ss += __shfl_xor(ss, o, 64);
        if (lane == 0) red[wv] = ss;
        __syncthreads();
        if (t == 0) {
            float tt = 0.f;
            #pragma unroll
            for (int i = 0; i < 8; ++i) tt += red[i];
            snorm = rsqrtf(tt);
        }
        __syncthreads();
        dst[t] = acc * snorm;
        __syncthreads();
    }

    float* fin = (iters & 1) ? vb : va;
    // w[t] = sum_c yT[c][t] v[c]  (coalesced)
    const float* Ytt = Yt + t;
    float accw = 0.f;
    #pragma unroll 4
    for (int c = 0; c < N; c += 8) {
        float4 s0 = *(const float4*)&fin[c];
        float4 s1 = *(const float4*)&fin[c + 4];
        const float* p = Ytt + (size_t)c * N;
        accw += p[0 * N] * s0.x;
        accw += p[1 * N] * s0.y;
        accw += p[2 * N] * s0.z;
        accw += p[3 * N] * s0.w;
        accw += p[4 * N] * s1.x;
        accw += p[5 * N] * s1.y;
        accw += p[6 * N] * s1.z;
        accw += p[7 * N] * s1.w;
    }
    vout[(size_t)b * N + t] = fin[t];
    wout[(size_t)b * N + t] = accw;
}

// ---------------- out[b,i,j] = w[b,i] * v[b,j] ----------------
__global__ __launch_bounds__(256) void k_outer(const float* __restrict__ v, const float* __restrict__ w,
                                               float* __restrict__ out) {
    int tid = blockIdx.x * 256 + threadIdx.x;
    int b = tid >> 16;
    int rem = tid & 65535;
    int i = rem >> 7;
    int j4 = rem & 127;
    float wi = w[(size_t)b * N + i];
    float4 vv = ((const float4*)(v + (size_t)b * N))[j4];
    float4 o = {wi * vv.x, wi * vv.y, wi * vv.z, wi * vv.w};
    ((float4*)out)[tid] = o;
}

extern "C" void kernel_launch(void* const* d_in, const int* in_sizes, int n_in,
                              void* d_out, int out_size, void* d_ws, size_t ws_size,
                              hipStream_t stream) {
    const float* x = (const float*)d_in[0];
    float* out = (float*)d_out;
    char* base = (char*)d_ws;

    const size_t PL = (size_t)NB * MAT * sizeof(ushort);   // 16 MB per plane array
    ushort* AH = (ushort*)(base);
    ushort* AM = (ushort*)(base + PL);
    ushort* BH = (ushort*)(base + 2 * PL);
    ushort* BM = (ushort*)(base + 3 * PL);
    float*  fs = (float*)(base + 4 * PL);
    float*  vv = fs + 512;
    float*  ww = vv + (size_t)NB * N;
    float*  yT = out;                            // stage yT fp32 in d_out (read by k_power before k_outer overwrites)

    hipMemsetAsync(fs, 0, 512 * sizeof(float), stream);
    k_luma<<<dim3(64, NB), 256, 0, stream>>>(x, yT, AH, AM);

    dim3 gg(4, 4, NB);
    // P1..P3 dual-plane (sensitive small-gap stages), P3 emits h-only; P4..P9 single-plane.
    k_gemm<2><<<gg, 256, 0, stream>>>(AH, AM, BH, BM,      nullptr,   fs + 0*32); // B      = yT yT^T
    k_gemm<2><<<gg, 256, 0, stream>>>(BH, BM, AH, AM,      fs + 0*32, fs + 1*32); // B^2
    k_gemm<2><<<gg, 256, 0, stream>>>(AH, AM, BH, nullptr, fs + 1*32, fs + 2*32); // B^4   (h only)
    k_gemm<1><<<gg, 256, 0, stream>>>(BH, nullptr, AH, nullptr, fs + 2*32, fs + 3*32); // B^8
    k_gemm<1><<<gg, 256, 0, stream>>>(AH, nullptr, BH, nullptr, fs + 3*32, fs + 4*32); // B^16
    k_gemm<1><<<gg, 256, 0, stream>>>(BH, nullptr, AH, nullptr, fs + 4*32, fs + 5*32); // B^32
    k_gemm<1><<<gg, 256, 0, stream>>>(AH, nullptr, BH, nullptr, fs + 5*32, fs + 6*32); // B^64
    k_gemm<1><<<gg, 256, 0, stream>>>(BH, nullptr, AH, nullptr, fs + 6*32, fs + 7*32); // B^128
    k_gemm<1><<<gg, 256, 0, stream>>>(AH, nullptr, BH, nullptr, fs + 7*32, nullptr);   // B^256 (h) -> BH

    k_power<<<NB, 512, 0, stream>>>(BH, yT, vv, ww, 8);
    k_outer<<<8192, 256, 0, stream>>>(vv, ww, out);
}